// Round 10
// baseline (3499.905 us; speedup 1.0000x reference)
//
#include <hip/hip_runtime.h>
#include <hip/hip_bf16.h>

#define B_ 256
#define S_ 512
#define H_ 1024
#define C_ 10

typedef unsigned long long u64;
typedef __attribute__((ext_vector_type(8))) short s8v;      // 8 bf16 (4 VGPRs) - MFMA A/B frag
typedef __attribute__((ext_vector_type(4))) float f4v;      // MFMA C/D frag
typedef __attribute__((ext_vector_type(4))) unsigned u4v;   // flag-line quad

// ---------------- workspace layout (bytes) ----------------
// [0, 32768)         : flags[256 blocks][4 waves] - 4 uints at the head of a 128B line
//                      per block (byte off = block*128 + w*4). flag word = steps
//                      completed BY THAT WAVE (stores drained). Single-writer,
//                      monotonic, relaxed agent STORE. Pollers read one dwordx4
//                      and take min4 -> block done.
// [32768, +524288)   : xT (S x B fp32)
// [557056, +524288)  : h0 (B x H bf16, FRAGMENT-LINEAR), zeroed per launch
// [1081344, +524288) : h1
// [1605632, +8388608): Wp (packed bf16 weights, fragment-linear, MFMA A operand)
//
// h fragment-linear layout: element (b, k) lives at
//   tb = b>>4, kc = k>>5, quad = (k>>3)&3, lane = quad*16 + (b&15), j = k&7
//   byte = ((tb*32 + kc)*64 + lane)*16 + j*2
//
// Sync (round 10) - split-poll + MFMA/tail overlap:
//  - wave 0 polls STAGE 1 (blocks 0..31 >= t -> chunks kc 0..15 readable),
//    releases tok=2t+1. wave 3 polls STAGE 2 (all 64 >= t), releases tok=2t+2.
//    Each wave pays at most ONE poll per step (r9: wave 0 paid both serially).
//  - waves 0-2: after batch-1 loads, WAITV(8) + MM(0..7) BEFORE the stage-2 spin:
//    the first quarter of the MFMA ladder overlaps the straggler tail.
//  - wave 3's stage-2 poll drains its batch-1 loads (embedded vmcnt(0)), so after
//    releasing tok it issues batch-2 and runs MM(0..15) immediately.
//  - per-wave flag publish right after the h-store drain (no LDS done_cnt chain);
//    xa prefetch issued AFTER the publish (its RTT is off the critical path; it is
//    drained by the next iteration's WAITV(0)/poll before the epilogue reads it).
//  - all h data traffic is LLC-bypass (sc0 sc1): no fences, no staleness cases.
//  - 2-buffer reuse safe: writers of buffer (t+1)&1 passed the all-64 stage-2 gate
//    (flags >= t) => every block finished its step-(t-1) reads of that buffer.

__global__ void prep_w(const float* __restrict__ wg, const float* __restrict__ wi,
                       const float* __restrict__ wf, const float* __restrict__ wo,
                       __hip_bfloat16* __restrict__ Wp) {
    int idx = blockIdx.x * 256 + threadIdx.x;        // 4*1024*128 = 524288 groups of 8
    int g   = idx >> 17;
    int rem = idx & 131071;
    int o   = rem >> 7;                              // out col 0..1023
    int kg  = rem & 127;                             // k0 = kg*8
    const float* src = (g == 0 ? wg : g == 1 ? wi : g == 2 ? wf : wo) + o * H_ + kg * 8;
    int kc   = kg >> 2;
    int quad = kg & 3;
    int lane = quad * 16 + (o & 15);
    int ot   = o >> 4;
    int blk  = (g * 64 + ot) * 32 + kc;
    __hip_bfloat16* dst = Wp + blk * 512 + lane * 8;
#pragma unroll
    for (int j = 0; j < 8; ++j) dst[j] = __float2bfloat16(src[j]);
}

// xT[t][b] = x[b][t]
__global__ void prep_x(const float* __restrict__ x, float* __restrict__ xT) {
    int i = blockIdx.x * 256 + threadIdx.x;          // 131072
    int t = i >> 8, b = i & 255;
    xT[i] = x[b * S_ + t];
}

__device__ __forceinline__ float sigmoid_f(float x) { return 1.0f / (1.0f + __expf(-x)); }
__device__ __forceinline__ float tanh_f(float x)    { return 2.0f / (1.0f + __expf(-2.0f * x)) - 1.0f; }

__device__ __forceinline__ float bf2f(unsigned short u) {
    union { unsigned i; float f; } x; x.i = ((unsigned)u) << 16; return x.f;
}
__device__ __forceinline__ unsigned short f2bf(float f) {
    union { __hip_bfloat16 h; unsigned short s; } x; x.h = __float2bfloat16(f); return x.s;
}

// LLC-direct, fully-pipelined h-fragment load.
#define LOADH(kc, g, off)                                                        \
    asm volatile("global_load_dwordx4 %0, %1, off offset:" #off " sc0 sc1"       \
                 : "=v"(hfrag[kc]) : "v"(hb[g]));

// counted wait + full scheduling fence (rule #18: MFMA must not hoist past the wait)
#define WAITV(n)                                                                 \
    asm volatile("s_waitcnt vmcnt(" #n ")" ::: "memory");                        \
    __builtin_amdgcn_sched_barrier(0);

#define MM(kc) {                                                                 \
    s8v hv = hfrag[kc];                                                          \
    acc0 = __builtin_amdgcn_mfma_f32_16x16x32_bf16(Wlds[0 * 2048 + (kc) * 64 + l], hv, acc0, 0, 0, 0); \
    acc1 = __builtin_amdgcn_mfma_f32_16x16x32_bf16(Wlds[1 * 2048 + (kc) * 64 + l], hv, acc1, 0, 0, 0); \
    acc2 = __builtin_amdgcn_mfma_f32_16x16x32_bf16(Wlds[2 * 2048 + (kc) * 64 + l], hv, acc2, 0, 0, 0); \
    acc3 = __builtin_amdgcn_mfma_f32_16x16x32_bf16(Wlds[3 * 2048 + (kc) * 64 + l], hv, acc3, 0, 0, 0); }

// one poll iteration: dwordx4 flag-line read (LLC) + min4; waitcnt inside the asm
// makes f4 valid (and drains any in-flight loads of this wave - accounted for).
#define POLL4(mnvar)                                                             \
    u4v f4_;                                                                     \
    asm volatile("global_load_dwordx4 %0, %1, off sc0 sc1\n\t"                   \
                 "s_waitcnt vmcnt(0)" : "=v"(f4_) : "v"(flpa));                  \
    unsigned a_ = f4_.x < f4_.y ? f4_.x : f4_.y;                                 \
    unsigned b_ = f4_.z < f4_.w ? f4_.z : f4_.w;                                 \
    unsigned mnvar = a_ < b_ ? a_ : b_;

__global__ __launch_bounds__(256, 1) void lstm_main(
    const float* __restrict__ xT,
    const float* __restrict__ wgx, const float* __restrict__ wix,
    const float* __restrict__ wfx, const float* __restrict__ wox,
    const float* __restrict__ bg,  const float* __restrict__ bi,
    const float* __restrict__ bf,  const float* __restrict__ bo,
    const __hip_bfloat16* __restrict__ Wp,
    __hip_bfloat16* __restrict__ h0, __hip_bfloat16* __restrict__ h1,
    const float* __restrict__ wph, const float* __restrict__ bp,
    float* __restrict__ out,
    unsigned* __restrict__ flags)
{
    // weights LDS-stationary: 4 gates x 32 kc x 64 lanes x 16B = 128 KB
    __shared__ s8v Wlds[4 * 32 * 64];
    __shared__ unsigned tok;        // monotonic: 2t+1 = chunks 0..15 ready, 2t+2 = all

    const int tid  = threadIdx.x;
    const int wgid = blockIdx.x;         // 256 blocks
    const int m    = wgid >> 6;          // batch group 0..3 (64 rows)
    const int n    = wgid & 63;          // out-tile 0..63 (16 hidden cols per gate)
    const int w    = tid >> 6;           // wave 0..3; wave 0 polls stage1, wave 3 stage2
    const int l    = tid & 63;
    const int quad = l >> 4;
    const int l16  = l & 15;
    const int b    = m * 64 + w * 16 + l16;  // this lane's batch row
    const int out0 = n * 16 + quad * 4;      // first of this lane's 4 hidden cols

    if (tid == 0) tok = 0u;

    // one-time: stage this block's weights into LDS (coalesced 16B cached loads)
    {
        const s8v* Wv = (const s8v*)Wp;
#pragma unroll
        for (int j = 0; j < 32; ++j) {
            int idx = j * 256 + tid;             // 0..8191
            int g   = idx >> 11;
            int rem = idx & 2047;                // kc*64 + lane
            Wlds[g * 2048 + rem] = Wv[((g * 64 + n) * 32) * 64 + rem];
        }
    }

    // per-lane gate params for the 4 consecutive hidden cols
    float wxg[4], wxi[4], wxf[4], wxo[4], bbg[4], bbi[4], bbf[4], bbo[4];
    *(float4*)wxg = *(const float4*)(wgx + out0);
    *(float4*)wxi = *(const float4*)(wix + out0);
    *(float4*)wxf = *(const float4*)(wfx + out0);
    *(float4*)wxo = *(const float4*)(wox + out0);
    *(float4*)bbg = *(const float4*)(bg + out0);
    *(float4*)bbi = *(const float4*)(bi + out0);
    *(float4*)bbf = *(const float4*)(bf + out0);
    *(float4*)bbo = *(const float4*)(bo + out0);

    float cs[4] = {0.f, 0.f, 0.f, 0.f};     // persistent cell state

    const u64 flpa   = (u64)(const void*)(flags + (u64)(m * 64 + l) * 32);  // watched line
    unsigned* myflag = flags + (u64)(m * 64 + n) * 32 + w;                  // my wave word

    // fragment-linear base offsets
    const u64 tbOff = (u64)((m * 4 + w) * 32768) + (u64)l * 16;   // consumer load base
    const int eidx_s = ((m * 4 + w) * 32 + (out0 >> 5)) * 64 + ((out0 >> 3) & 3) * 16 + l16;
    const u64 stOff  = (u64)eidx_s * 16 + (u64)(out0 & 7) * 2;    // producer store offset
    u64 xaddr = (u64)(const void*)xT + (u64)b * 4;                // xT[t*B + b], t=0
    const u64 h0a = (u64)(const void*)h0;
    const u64 h1a = (u64)(const void*)h1;

    __syncthreads();                         // LDS weights + tok ready

    // prefetch xa for t=0; it is drained (poll vmcnt(0) or WAITV(0)) before first use
    float xa_nxt;
    asm volatile("global_load_dword %0, %1, off" : "=v"(xa_nxt) : "v"(xaddr));

    for (int t = 0; t < S_; ++t) {
        const unsigned tu = (unsigned)t;
        const u64 hinB  = (t & 1) ? h1a : h0a;
        const u64 houtB = (t & 1) ? h0a : h1a;

        // ---- stage 1: blocks 0..31 (producers of chunks kc 0..15) done with t-1 ----
        if (w == 0) {
            for (;;) {
                POLL4(mn)
                if ((__ballot(mn < tu) & 0xFFFFFFFFull) == 0ull) break;
            }
            if (l == 0)
                __hip_atomic_store(&tok, 2u * tu + 1u, __ATOMIC_RELAXED,
                                   __HIP_MEMORY_SCOPE_WORKGROUP);
        } else {
            while (__hip_atomic_load(&tok, __ATOMIC_RELAXED,
                                     __HIP_MEMORY_SCOPE_WORKGROUP) < 2u * tu + 1u) { }
        }
        __builtin_amdgcn_sched_barrier(0);

        // 8 base addresses (13-bit imm offset only reaches 4095; kc stride is 1024B)
        u64 hb[8];
        u64 base = hinB + tbOff;
#pragma unroll
        for (int g = 0; g < 8; ++g) hb[g] = base + (u64)g * 4096;

        s8v hfrag[32];
        // batch-1 loads (kc 0..15): RTT overlaps the straggler tail of blocks 32..63
        LOADH( 0, 0, 0) LOADH( 1, 0, 1024) LOADH( 2, 0, 2048) LOADH( 3, 0, 3072)
        LOADH( 4, 1, 0) LOADH( 5, 1, 1024) LOADH( 6, 1, 2048) LOADH( 7, 1, 3072)
        LOADH( 8, 2, 0) LOADH( 9, 2, 1024) LOADH(10, 2, 2048) LOADH(11, 2, 3072)
        LOADH(12, 3, 0) LOADH(13, 3, 1024) LOADH(14, 3, 2048) LOADH(15, 3, 3072)

        f4v acc0 = {0.f, 0.f, 0.f, 0.f}, acc1 = acc0, acc2 = acc0, acc3 = acc0;

        if (w == 3) {
            // ---- wave 3 polls stage 2 (all 64 done); poll drains batch-1 loads ----
            for (;;) {
                POLL4(mn)
                if (__ballot(mn < tu) == 0ull) break;
            }
            if (l == 0)
                __hip_atomic_store(&tok, 2u * tu + 2u, __ATOMIC_RELAXED,
                                   __HIP_MEMORY_SCOPE_WORKGROUP);
            __builtin_amdgcn_sched_barrier(0);
            LOADH(16, 4, 0) LOADH(17, 4, 1024) LOADH(18, 4, 2048) LOADH(19, 4, 3072)
            LOADH(20, 5, 0) LOADH(21, 5, 1024) LOADH(22, 5, 2048) LOADH(23, 5, 3072)
            LOADH(24, 6, 0) LOADH(25, 6, 1024) LOADH(26, 6, 2048) LOADH(27, 6, 3072)
            LOADH(28, 7, 0) LOADH(29, 7, 1024) LOADH(30, 7, 2048) LOADH(31, 7, 3072)
            // batch-1 already in regs (drained by the poll) -> 16 MMs immediately;
            // batch-2 (16 outstanding) overlaps them.
            MM(0)  MM(1)  MM(2)  MM(3)  MM(4)  MM(5)  MM(6)  MM(7)
            MM(8)  MM(9)  MM(10) MM(11) MM(12) MM(13) MM(14) MM(15)
            WAITV(8)
            MM(16) MM(17) MM(18) MM(19) MM(20) MM(21) MM(22) MM(23)
            WAITV(0)
            MM(24) MM(25) MM(26) MM(27) MM(28) MM(29) MM(30) MM(31)
        } else {
            // ---- waves 0-2: first quarter of the ladder overlaps the stage-2 wait ----
            // outstanding <= 17 (xa oldest + 16); WAITV(8) -> kc 0..7 landed.
            WAITV(8)
            MM(0)  MM(1)  MM(2)  MM(3)  MM(4)  MM(5)  MM(6)  MM(7)
            while (__hip_atomic_load(&tok, __ATOMIC_RELAXED,
                                     __HIP_MEMORY_SCOPE_WORKGROUP) < 2u * tu + 2u) { }
            __builtin_amdgcn_sched_barrier(0);
            LOADH(16, 4, 0) LOADH(17, 4, 1024) LOADH(18, 4, 2048) LOADH(19, 4, 3072)
            LOADH(20, 5, 0) LOADH(21, 5, 1024) LOADH(22, 5, 2048) LOADH(23, 5, 3072)
            LOADH(24, 6, 0) LOADH(25, 6, 1024) LOADH(26, 6, 2048) LOADH(27, 6, 3072)
            LOADH(28, 7, 0) LOADH(29, 7, 1024) LOADH(30, 7, 2048) LOADH(31, 7, 3072)
            // outstanding = 8 (kc 8..15) + 16 (batch-2) = 24
            WAITV(16)
            MM(8)  MM(9)  MM(10) MM(11) MM(12) MM(13) MM(14) MM(15)
            WAITV(8)
            MM(16) MM(17) MM(18) MM(19) MM(20) MM(21) MM(22) MM(23)
            WAITV(0)
            MM(24) MM(25) MM(26) MM(27) MM(28) MM(29) MM(30) MM(31)
        }

        // epilogue: D row (quad*4+r) = hidden col out0+r, D col (l16) = batch b
        // xa_nxt landed: every path above ended with a vmcnt(0) (WAITV(0) or poll).
        float xa = xa_nxt;
        unsigned short hs[4];
#pragma unroll
        for (int r = 0; r < 4; ++r) {
            float pg = acc0[r] + xa * wxg[r] + bbg[r];
            float pi = acc1[r] + xa * wxi[r] + bbi[r];
            float pf = acc2[r] + xa * wxf[r] + bbf[r];
            float po = acc3[r] + xa * wxo[r] + bbo[r];
            float gv = tanh_f(pg);
            float iv = sigmoid_f(pi);
            float fv = sigmoid_f(pf);
            float ov = sigmoid_f(po);
            float cn = gv * iv + cs[r] * fv;
            cs[r] = cn;
            hs[r] = f2bf(tanh_f(cn) * ov);
        }
        union { unsigned short s[4]; u64 q; } hp_;
        hp_.s[0] = hs[0]; hp_.s[1] = hs[1]; hp_.s[2] = hs[2]; hp_.s[3] = hs[3];
        // one 8B write-through (LLC) store into the fragment-linear slot
        __hip_atomic_store((u64*)(houtB + stOff), hp_.q,
                           __ATOMIC_RELAXED, __HIP_MEMORY_SCOPE_AGENT);

        // drain the h store to the coherence point, publish THIS WAVE's flag word,
        // then issue next step's xa prefetch (off the critical path; drained before
        // its use by next iteration's vmcnt(0) points).
        WAITV(0)
        __hip_atomic_store(myflag, tu + 1u, __ATOMIC_RELAXED, __HIP_MEMORY_SCOPE_AGENT);
        xaddr += (u64)B_ * 4;
        asm volatile("global_load_dword %0, %1, off" : "=v"(xa_nxt) : "v"(xaddr));
    }

    // ---- final rendezvous: all blocks of the group done with step S-1 ----
    if (w == 0) {
        for (;;) {
            POLL4(mn)
            if (__ballot(mn < (unsigned)S_) == 0ull) break;
        }
        if (l == 0)
            __hip_atomic_store(&tok, 2u * (unsigned)S_ + 1u, __ATOMIC_RELAXED,
                               __HIP_MEMORY_SCOPE_WORKGROUP);
    }
    while (__hip_atomic_load(&tok, __ATOMIC_RELAXED,
                             __HIP_MEMORY_SCOPE_WORKGROUP) < 2u * (unsigned)S_ + 1u) { }
    __builtin_amdgcn_sched_barrier(0);

    // projection restricted to own group's rows: out[row][cc], rows [64m, 64m+64)
    // final h is h0 (t=511 odd wrote h0); bypass atomic loads -> always fresh.
    const __hip_bfloat16* hf = h0;
    int wig = n * 4 + w;                     // wave index in group, 0..255
    for (int p = wig; p < 64 * C_; p += 256) {
        int row = m * 64 + p / C_;
        int cc  = p % C_;
        int tb  = row >> 4, bl = row & 15;
        const float* wr = wph + cc * H_;
        float acc = 0.f;
#pragma unroll
        for (int j = 0; j < 4; ++j) {
            int k   = j * 256 + l * 4;
            int kc  = k >> 5;
            int qd  = (k >> 3) & 3;
            const u64* hp = (const u64*)((const char*)hf
                              + ((size_t)((tb * 32 + kc) * 64 + qd * 16 + bl)) * 16
                              + (size_t)(k & 7) * 2);
            u64 hv4 = __hip_atomic_load(hp, __ATOMIC_RELAXED, __HIP_MEMORY_SCOPE_AGENT);
            union { u64 q; unsigned short s[4]; } u_; u_.q = hv4;
            float4 wv = *(const float4*)(wr + k);
            acc += bf2f(u_.s[0]) * wv.x + bf2f(u_.s[1]) * wv.y
                 + bf2f(u_.s[2]) * wv.z + bf2f(u_.s[3]) * wv.w;
        }
#pragma unroll
        for (int off = 32; off > 0; off >>= 1) acc += __shfl_down(acc, off, 64);
        if (l == 0) out[row * C_ + cc] = acc + bp[cc];
    }
}

extern "C" void kernel_launch(void* const* d_in, const int* in_sizes, int n_in,
                              void* d_out, int out_size, void* d_ws, size_t ws_size,
                              hipStream_t stream) {
    const float* x   = (const float*)d_in[0];
    const float* wgx = (const float*)d_in[1];
    const float* wix = (const float*)d_in[2];
    const float* wfx = (const float*)d_in[3];
    const float* wox = (const float*)d_in[4];
    const float* wgh = (const float*)d_in[5];
    const float* wih = (const float*)d_in[6];
    const float* wfh = (const float*)d_in[7];
    const float* woh = (const float*)d_in[8];
    const float* wph = (const float*)d_in[9];
    const float* bg  = (const float*)d_in[10];
    const float* bi  = (const float*)d_in[11];
    const float* bf  = (const float*)d_in[12];
    const float* bo  = (const float*)d_in[13];
    const float* bp  = (const float*)d_in[14];
    float* out = (float*)d_out;

    char* ws = (char*)d_ws;
    unsigned*       flags = (unsigned*)ws;
    float*          xT    = (float*)(ws + 32768);
    __hip_bfloat16* h0    = (__hip_bfloat16*)(ws + 32768 + 524288);
    __hip_bfloat16* h1    = (__hip_bfloat16*)(ws + 32768 + 2 * 524288);
    __hip_bfloat16* Wp    = (__hip_bfloat16*)(ws + 32768 + 3 * 524288);

    hipMemsetAsync(flags, 0, 32768, stream);              // spread flag lines = 0
    hipMemsetAsync(h0, 0, 524288, stream);                // h_0 = 0
    prep_x<<<512, 256, 0, stream>>>(x, xT);
    prep_w<<<2048, 256, 0, stream>>>(wgh, wih, wfh, woh, Wp);
    lstm_main<<<256, 256, 0, stream>>>(xT, wgx, wix, wfx, wox, bg, bi, bf, bo,
                                       Wp, h0, h1, wph, bp, out, flags);
}

// Round 11
// 3318.521 us; speedup vs baseline: 1.0547x; 1.0547x over previous
//
#include <hip/hip_runtime.h>
#include <hip/hip_bf16.h>

#define B_ 256
#define S_ 512
#define H_ 1024
#define C_ 10

typedef unsigned long long u64;
typedef __attribute__((ext_vector_type(8))) short s8v;      // 8 bf16 (4 VGPRs) - MFMA A/B frag
typedef __attribute__((ext_vector_type(4))) float f4v;      // MFMA C/D frag
typedef __attribute__((ext_vector_type(4))) unsigned u4v;   // flag-line quad

// ---------------- workspace layout (bytes) ----------------
// [0, 32768)         : flags[256 blocks][4 waves] - 4 uints at the head of a 128B line
//                      per block (byte off = block*128 + w*4). word = steps completed
//                      by that wave (h stores drained). Single-writer, monotonic,
//                      relaxed agent STORE. Pollers read one dwordx4, min4 = block done.
// [32768, +524288)   : xT (S x B fp32)
// [557056, +524288)  : h0 (B x H bf16, FRAGMENT-LINEAR), zeroed per launch
// [1081344, +524288) : h1
// [1605632, +8388608): Wp (packed bf16 weights, fragment-linear, MFMA A operand)
//
// h fragment-linear layout: element (b, k) lives at
//   tb = b>>4, kc = k>>5, quad = (k>>3)&3, lane = quad*16 + (b&15), j = k&7
//   byte = ((tb*32 + kc)*64 + lane)*16 + j*2
//
// Sync (round 11) = r9 skeleton (best: 3052us) + three deltas:
//  - wave 0 polls stage 1 (blocks 0..31 >= t). Its ballot covers ALL 64 lanes, so if
//    the full group already passed, it releases tok=2t+2 directly (skips the second
//    poll RTT). Otherwise releases 2t+1 and re-polls for stage 2 as in r9.
//  - per-wave flag words published right after the h-store drain (no LDS RMW chain).
//  - xa prefetch issued AFTER the flag publish (off the critical path; drained by the
//    next iteration's counted waits - extra in-flight entries are oldest, so WAITV
//    guarantees are preserved).
//  - all h data traffic is LLC-bypass (sc0 sc1): no fences, no staleness cases.
//  - 2-buffer reuse safe: writers of buffer (t+1)&1 passed the all-64 gate (flags>=t)
//    => every block finished its step-(t-1) reads of that buffer.

__global__ void prep_w(const float* __restrict__ wg, const float* __restrict__ wi,
                       const float* __restrict__ wf, const float* __restrict__ wo,
                       __hip_bfloat16* __restrict__ Wp) {
    int idx = blockIdx.x * 256 + threadIdx.x;        // 4*1024*128 = 524288 groups of 8
    int g   = idx >> 17;
    int rem = idx & 131071;
    int o   = rem >> 7;                              // out col 0..1023
    int kg  = rem & 127;                             // k0 = kg*8
    const float* src = (g == 0 ? wg : g == 1 ? wi : g == 2 ? wf : wo) + o * H_ + kg * 8;
    int kc   = kg >> 2;
    int quad = kg & 3;
    int lane = quad * 16 + (o & 15);
    int ot   = o >> 4;
    int blk  = (g * 64 + ot) * 32 + kc;
    __hip_bfloat16* dst = Wp + blk * 512 + lane * 8;
#pragma unroll
    for (int j = 0; j < 8; ++j) dst[j] = __float2bfloat16(src[j]);
}

// xT[t][b] = x[b][t]
__global__ void prep_x(const float* __restrict__ x, float* __restrict__ xT) {
    int i = blockIdx.x * 256 + threadIdx.x;          // 131072
    int t = i >> 8, b = i & 255;
    xT[i] = x[b * S_ + t];
}

__device__ __forceinline__ float sigmoid_f(float x) { return 1.0f / (1.0f + __expf(-x)); }
__device__ __forceinline__ float tanh_f(float x)    { return 2.0f / (1.0f + __expf(-2.0f * x)) - 1.0f; }

__device__ __forceinline__ float bf2f(unsigned short u) {
    union { unsigned i; float f; } x; x.i = ((unsigned)u) << 16; return x.f;
}
__device__ __forceinline__ unsigned short f2bf(float f) {
    union { __hip_bfloat16 h; unsigned short s; } x; x.h = __float2bfloat16(f); return x.s;
}

// LLC-direct, fully-pipelined h-fragment load.
#define LOADH(kc, g, off)                                                        \
    asm volatile("global_load_dwordx4 %0, %1, off offset:" #off " sc0 sc1"       \
                 : "=v"(hfrag[kc]) : "v"(hb[g]));

// counted wait + full scheduling fence (rule #18: MFMA must not hoist past the wait)
#define WAITV(n)                                                                 \
    asm volatile("s_waitcnt vmcnt(" #n ")" ::: "memory");                        \
    __builtin_amdgcn_sched_barrier(0);

#define MM(kc) {                                                                 \
    s8v hv = hfrag[kc];                                                          \
    acc0 = __builtin_amdgcn_mfma_f32_16x16x32_bf16(Wlds[0 * 2048 + (kc) * 64 + l], hv, acc0, 0, 0, 0); \
    acc1 = __builtin_amdgcn_mfma_f32_16x16x32_bf16(Wlds[1 * 2048 + (kc) * 64 + l], hv, acc1, 0, 0, 0); \
    acc2 = __builtin_amdgcn_mfma_f32_16x16x32_bf16(Wlds[2 * 2048 + (kc) * 64 + l], hv, acc2, 0, 0, 0); \
    acc3 = __builtin_amdgcn_mfma_f32_16x16x32_bf16(Wlds[3 * 2048 + (kc) * 64 + l], hv, acc3, 0, 0, 0); }

// one poll iteration: dwordx4 flag-line read (LLC) + min4; the embedded waitcnt makes
// f4_ valid (and drains this wave's in-flight loads - accounted for at the call sites).
#define POLL4(mnvar)                                                             \
    u4v f4_;                                                                     \
    asm volatile("global_load_dwordx4 %0, %1, off sc0 sc1\n\t"                   \
                 "s_waitcnt vmcnt(0)" : "=v"(f4_) : "v"(flpa));                  \
    unsigned a_ = f4_.x < f4_.y ? f4_.x : f4_.y;                                 \
    unsigned b_ = f4_.z < f4_.w ? f4_.z : f4_.w;                                 \
    unsigned mnvar = a_ < b_ ? a_ : b_;

__global__ __launch_bounds__(256, 1) void lstm_main(
    const float* __restrict__ xT,
    const float* __restrict__ wgx, const float* __restrict__ wix,
    const float* __restrict__ wfx, const float* __restrict__ wox,
    const float* __restrict__ bg,  const float* __restrict__ bi,
    const float* __restrict__ bf,  const float* __restrict__ bo,
    const __hip_bfloat16* __restrict__ Wp,
    __hip_bfloat16* __restrict__ h0, __hip_bfloat16* __restrict__ h1,
    const float* __restrict__ wph, const float* __restrict__ bp,
    float* __restrict__ out,
    unsigned* __restrict__ flags)
{
    // weights LDS-stationary: 4 gates x 32 kc x 64 lanes x 16B = 128 KB
    __shared__ s8v Wlds[4 * 32 * 64];
    __shared__ unsigned tok;        // monotonic: 2t+1 = chunks 0..15 ready, 2t+2 = all

    const int tid  = threadIdx.x;
    const int wgid = blockIdx.x;         // 256 blocks
    const int m    = wgid >> 6;          // batch group 0..3 (64 rows)
    const int n    = wgid & 63;          // out-tile 0..63 (16 hidden cols per gate)
    const int w    = tid >> 6;           // wave 0..3; wave 0 is the poller
    const int l    = tid & 63;
    const int quad = l >> 4;
    const int l16  = l & 15;
    const int b    = m * 64 + w * 16 + l16;  // this lane's batch row
    const int out0 = n * 16 + quad * 4;      // first of this lane's 4 hidden cols

    if (tid == 0) tok = 0u;

    // one-time: stage this block's weights into LDS (coalesced 16B cached loads)
    {
        const s8v* Wv = (const s8v*)Wp;
#pragma unroll
        for (int j = 0; j < 32; ++j) {
            int idx = j * 256 + tid;             // 0..8191
            int g   = idx >> 11;
            int rem = idx & 2047;                // kc*64 + lane
            Wlds[g * 2048 + rem] = Wv[((g * 64 + n) * 32) * 64 + rem];
        }
    }

    // per-lane gate params for the 4 consecutive hidden cols
    float wxg[4], wxi[4], wxf[4], wxo[4], bbg[4], bbi[4], bbf[4], bbo[4];
    *(float4*)wxg = *(const float4*)(wgx + out0);
    *(float4*)wxi = *(const float4*)(wix + out0);
    *(float4*)wxf = *(const float4*)(wfx + out0);
    *(float4*)wxo = *(const float4*)(wox + out0);
    *(float4*)bbg = *(const float4*)(bg + out0);
    *(float4*)bbi = *(const float4*)(bi + out0);
    *(float4*)bbf = *(const float4*)(bf + out0);
    *(float4*)bbo = *(const float4*)(bo + out0);

    float cs[4] = {0.f, 0.f, 0.f, 0.f};     // persistent cell state

    const u64 flpa   = (u64)(const void*)(flags + (u64)(m * 64 + l) * 32);  // watched line
    unsigned* myflag = flags + (u64)(m * 64 + n) * 32 + w;                  // my wave word

    // fragment-linear base offsets
    const u64 tbOff = (u64)((m * 4 + w) * 32768) + (u64)l * 16;   // consumer load base
    const int eidx_s = ((m * 4 + w) * 32 + (out0 >> 5)) * 64 + ((out0 >> 3) & 3) * 16 + l16;
    const u64 stOff  = (u64)eidx_s * 16 + (u64)(out0 & 7) * 2;    // producer store offset
    u64 xaddr = (u64)(const void*)xT + (u64)b * 4;                // xT[t*B + b], t=0
    const u64 h0a = (u64)(const void*)h0;
    const u64 h1a = (u64)(const void*)h1;

    __syncthreads();                         // LDS weights + tok ready

    // prefetch xa for t=0; drained by the first counted waits before its use
    float xa_nxt;
    asm volatile("global_load_dword %0, %1, off" : "=v"(xa_nxt) : "v"(xaddr));

    for (int t = 0; t < S_; ++t) {
        const unsigned tu = (unsigned)t;
        const u64 hinB  = (t & 1) ? h1a : h0a;
        const u64 houtB = (t & 1) ? h0a : h1a;

        bool fd = false;                     // "full group done" seen at stage-1 detect

        // ---- stage 1: blocks 0..31 done; opportunistically detect all-64 too ----
        if (w == 0) {
            for (;;) {
                POLL4(mn)
                u64 bal = __ballot(mn < tu);
                if ((bal & 0xFFFFFFFFull) == 0ull) { fd = (bal == 0ull); break; }
                __builtin_amdgcn_s_sleep(1);
            }
            if (l == 0)
                __hip_atomic_store(&tok, fd ? 2u * tu + 2u : 2u * tu + 1u,
                                   __ATOMIC_RELAXED, __HIP_MEMORY_SCOPE_WORKGROUP);
        } else {
            while (__hip_atomic_load(&tok, __ATOMIC_RELAXED,
                                     __HIP_MEMORY_SCOPE_WORKGROUP) < 2u * tu + 1u) { }
        }
        __builtin_amdgcn_sched_barrier(0);

        // 8 base addresses (13-bit imm offset only reaches 4095; kc stride is 1024B)
        u64 hb[8];
        u64 base = hinB + tbOff;
#pragma unroll
        for (int g = 0; g < 8; ++g) hb[g] = base + (u64)g * 4096;

        s8v hfrag[32];
        // batch-1 loads (kc 0..15): RTT overlaps the straggler tail of blocks 32..63
        LOADH( 0, 0, 0) LOADH( 1, 0, 1024) LOADH( 2, 0, 2048) LOADH( 3, 0, 3072)
        LOADH( 4, 1, 0) LOADH( 5, 1, 1024) LOADH( 6, 1, 2048) LOADH( 7, 1, 3072)
        LOADH( 8, 2, 0) LOADH( 9, 2, 1024) LOADH(10, 2, 2048) LOADH(11, 2, 3072)
        LOADH(12, 3, 0) LOADH(13, 3, 1024) LOADH(14, 3, 2048) LOADH(15, 3, 3072)

        // ---- stage 2: all 64 blocks done (skipped when stage-1 already saw all-64) ----
        if (w == 0) {
            if (!fd) {
                for (;;) {
                    POLL4(mn)
                    if (__ballot(mn < tu) == 0ull) break;
                }
                if (l == 0)
                    __hip_atomic_store(&tok, 2u * tu + 2u, __ATOMIC_RELAXED,
                                       __HIP_MEMORY_SCOPE_WORKGROUP);
            }
        } else {
            while (__hip_atomic_load(&tok, __ATOMIC_RELAXED,
                                     __HIP_MEMORY_SCOPE_WORKGROUP) < 2u * tu + 2u) { }
        }
        __builtin_amdgcn_sched_barrier(0);

        LOADH(16, 4, 0) LOADH(17, 4, 1024) LOADH(18, 4, 2048) LOADH(19, 4, 3072)
        LOADH(20, 5, 0) LOADH(21, 5, 1024) LOADH(22, 5, 2048) LOADH(23, 5, 3072)
        LOADH(24, 6, 0) LOADH(25, 6, 1024) LOADH(26, 6, 2048) LOADH(27, 6, 3072)
        LOADH(28, 7, 0) LOADH(29, 7, 1024) LOADH(30, 7, 2048) LOADH(31, 7, 3072)

        f4v acc0 = {0.f, 0.f, 0.f, 0.f}, acc1 = acc0, acc2 = acc0, acc3 = acc0;
        // Outstanding entering the ladder (per wave): <= flag-store + xa + 32 frags.
        // Older non-frag entries (flag, xa) only make the counted waits conservative:
        // WAITV(24) retires everything except the newest 24 -> kc 0..7 landed, etc.
        // (Wave 0 paths that polled have fewer outstanding - strictly safe.)
        WAITV(24)
        MM(0)  MM(1)  MM(2)  MM(3)  MM(4)  MM(5)  MM(6)  MM(7)
        WAITV(16)
        MM(8)  MM(9)  MM(10) MM(11) MM(12) MM(13) MM(14) MM(15)
        WAITV(8)
        MM(16) MM(17) MM(18) MM(19) MM(20) MM(21) MM(22) MM(23)
        WAITV(0)
        MM(24) MM(25) MM(26) MM(27) MM(28) MM(29) MM(30) MM(31)

        // epilogue: D row (quad*4+r) = hidden col out0+r, D col (l16) = batch b
        // xa_nxt landed (WAITV(0) drained everything).
        float xa = xa_nxt;
        unsigned short hs[4];
#pragma unroll
        for (int r = 0; r < 4; ++r) {
            float pg = acc0[r] + xa * wxg[r] + bbg[r];
            float pi = acc1[r] + xa * wxi[r] + bbi[r];
            float pf = acc2[r] + xa * wxf[r] + bbf[r];
            float po = acc3[r] + xa * wxo[r] + bbo[r];
            float gv = tanh_f(pg);
            float iv = sigmoid_f(pi);
            float fv = sigmoid_f(pf);
            float ov = sigmoid_f(po);
            float cn = gv * iv + cs[r] * fv;
            cs[r] = cn;
            hs[r] = f2bf(tanh_f(cn) * ov);
        }
        union { unsigned short s[4]; u64 q; } hp_;
        hp_.s[0] = hs[0]; hp_.s[1] = hs[1]; hp_.s[2] = hs[2]; hp_.s[3] = hs[3];
        // one 8B write-through (LLC) store into the fragment-linear slot
        __hip_atomic_store((u64*)(houtB + stOff), hp_.q,
                           __ATOMIC_RELAXED, __HIP_MEMORY_SCOPE_AGENT);

        // drain the h store, publish THIS WAVE's flag word immediately, then issue the
        // next xa prefetch (flag store + xa stay in flight; both are oldest entries
        // next iteration, so the counted waits remain exact).
        WAITV(0)
        __hip_atomic_store(myflag, tu + 1u, __ATOMIC_RELAXED, __HIP_MEMORY_SCOPE_AGENT);
        xaddr += (u64)B_ * 4;
        asm volatile("global_load_dword %0, %1, off" : "=v"(xa_nxt) : "v"(xaddr));
    }

    // ---- final rendezvous: all blocks of the group done with step S-1 ----
    if (w == 0) {
        for (;;) {
            POLL4(mn)
            if (__ballot(mn < (unsigned)S_) == 0ull) break;
        }
        if (l == 0)
            __hip_atomic_store(&tok, 2u * (unsigned)S_ + 1u, __ATOMIC_RELAXED,
                               __HIP_MEMORY_SCOPE_WORKGROUP);
    }
    while (__hip_atomic_load(&tok, __ATOMIC_RELAXED,
                             __HIP_MEMORY_SCOPE_WORKGROUP) < 2u * (unsigned)S_ + 1u) { }
    __builtin_amdgcn_sched_barrier(0);

    // projection restricted to own group's rows: out[row][cc], rows [64m, 64m+64)
    // final h is h0 (t=511 odd wrote h0); bypass atomic loads -> always fresh.
    const __hip_bfloat16* hf = h0;
    int wig = n * 4 + w;                     // wave index in group, 0..255
    for (int p = wig; p < 64 * C_; p += 256) {
        int row = m * 64 + p / C_;
        int cc  = p % C_;
        int tb  = row >> 4, bl = row & 15;
        const float* wr = wph + cc * H_;
        float acc = 0.f;
#pragma unroll
        for (int j = 0; j < 4; ++j) {
            int k   = j * 256 + l * 4;
            int kc  = k >> 5;
            int qd  = (k >> 3) & 3;
            const u64* hp = (const u64*)((const char*)hf
                              + ((size_t)((tb * 32 + kc) * 64 + qd * 16 + bl)) * 16
                              + (size_t)(k & 7) * 2);
            u64 hv4 = __hip_atomic_load(hp, __ATOMIC_RELAXED, __HIP_MEMORY_SCOPE_AGENT);
            union { u64 q; unsigned short s[4]; } u_; u_.q = hv4;
            float4 wv = *(const float4*)(wr + k);
            acc += bf2f(u_.s[0]) * wv.x + bf2f(u_.s[1]) * wv.y
                 + bf2f(u_.s[2]) * wv.z + bf2f(u_.s[3]) * wv.w;
        }
#pragma unroll
        for (int off = 32; off > 0; off >>= 1) acc += __shfl_down(acc, off, 64);
        if (l == 0) out[row * C_ + cc] = acc + bp[cc];
    }
}

extern "C" void kernel_launch(void* const* d_in, const int* in_sizes, int n_in,
                              void* d_out, int out_size, void* d_ws, size_t ws_size,
                              hipStream_t stream) {
    const float* x   = (const float*)d_in[0];
    const float* wgx = (const float*)d_in[1];
    const float* wix = (const float*)d_in[2];
    const float* wfx = (const float*)d_in[3];
    const float* wox = (const float*)d_in[4];
    const float* wgh = (const float*)d_in[5];
    const float* wih = (const float*)d_in[6];
    const float* wfh = (const float*)d_in[7];
    const float* woh = (const float*)d_in[8];
    const float* wph = (const float*)d_in[9];
    const float* bg  = (const float*)d_in[10];
    const float* bi  = (const float*)d_in[11];
    const float* bf  = (const float*)d_in[12];
    const float* bo  = (const float*)d_in[13];
    const float* bp  = (const float*)d_in[14];
    float* out = (float*)d_out;

    char* ws = (char*)d_ws;
    unsigned*       flags = (unsigned*)ws;
    float*          xT    = (float*)(ws + 32768);
    __hip_bfloat16* h0    = (__hip_bfloat16*)(ws + 32768 + 524288);
    __hip_bfloat16* h1    = (__hip_bfloat16*)(ws + 32768 + 2 * 524288);
    __hip_bfloat16* Wp    = (__hip_bfloat16*)(ws + 32768 + 3 * 524288);

    hipMemsetAsync(flags, 0, 32768, stream);              // spread flag lines = 0
    hipMemsetAsync(h0, 0, 524288, stream);                // h_0 = 0
    prep_x<<<512, 256, 0, stream>>>(x, xT);
    prep_w<<<2048, 256, 0, stream>>>(wgh, wih, wfh, woh, Wp);
    lstm_main<<<256, 256, 0, stream>>>(xT, wgx, wix, wfx, wox, bg, bi, bf, bo,
                                       Wp, h0, h1, wph, bp, out, flags);
}

// Round 12
// 3023.760 us; speedup vs baseline: 1.1575x; 1.0975x over previous
//
#include <hip/hip_runtime.h>
#include <hip/hip_bf16.h>

#define B_ 256
#define S_ 512
#define H_ 1024
#define C_ 10

typedef unsigned long long u64;
typedef __attribute__((ext_vector_type(8))) short s8v;      // 8 bf16 (4 VGPRs) - MFMA A/B frag
typedef __attribute__((ext_vector_type(4))) float f4v;      // MFMA C/D frag

// ---------------- workspace layout (bytes) ----------------
// [0, 32768)         : flags[256 blocks], ONE uint per 128B line (index (m*64+n)*32).
//                      flag = steps completed by that block. Updated by ONE relaxed
//                      agent STORE per block-step (single writer, monotonic, no RMW).
// [32768, +524288)   : xT (S x B fp32)
// [557056, +524288)  : h0 (B x H bf16, FRAGMENT-LINEAR), zeroed per launch
// [1081344, +524288) : h1
// [1605632, +8388608): Wp (packed bf16 weights, fragment-linear, MFMA A operand)
//
// h fragment-linear layout: element (b, k) lives at
//   tb = b>>4, kc = k>>5, quad = (k>>3)&3, lane = quad*16 + (b&15), j = k&7
//   byte = ((tb*32 + kc)*64 + lane)*16 + j*2
//
// Sync (round 12) = EXACT r9 skeleton (best: 3052us) + two isolated chain-shortening
// deltas (r11's per-wave flag words are REVERTED - they made the flag line 4-writer
// and regressed):
//  - opportunistic full release: wave 0's stage-1 ballot covers all 64 lanes; when it
//    shows the whole group done, release tok=2t+2 directly and skip the stage-2 poll
//    RTT. Worst case identical to r9.
//  - publish-before-prefetch: h-store -> vmcnt(0) drain -> LDS done_cnt chain -> flag
//    store -> THEN xa prefetch. r9 had the xa prefetch inside the drain, putting its
//    RTT on the publish edge every step. Flag store + xa ride in flight as the two
//    OLDEST vmcnt entries, so every counted wait below stays conservative.
//  - all h data traffic is LLC-bypass (sc0 sc1): no fences, no staleness cases.
//  - 2-buffer reuse safe: writers of buffer (t+1)&1 passed the all-64 gate (flags>=t)
//    => every block finished its step-(t-1) reads of that buffer.

__global__ void prep_w(const float* __restrict__ wg, const float* __restrict__ wi,
                       const float* __restrict__ wf, const float* __restrict__ wo,
                       __hip_bfloat16* __restrict__ Wp) {
    int idx = blockIdx.x * 256 + threadIdx.x;        // 4*1024*128 = 524288 groups of 8
    int g   = idx >> 17;
    int rem = idx & 131071;
    int o   = rem >> 7;                              // out col 0..1023
    int kg  = rem & 127;                             // k0 = kg*8
    const float* src = (g == 0 ? wg : g == 1 ? wi : g == 2 ? wf : wo) + o * H_ + kg * 8;
    int kc   = kg >> 2;
    int quad = kg & 3;
    int lane = quad * 16 + (o & 15);
    int ot   = o >> 4;
    int blk  = (g * 64 + ot) * 32 + kc;
    __hip_bfloat16* dst = Wp + blk * 512 + lane * 8;
#pragma unroll
    for (int j = 0; j < 8; ++j) dst[j] = __float2bfloat16(src[j]);
}

// xT[t][b] = x[b][t]
__global__ void prep_x(const float* __restrict__ x, float* __restrict__ xT) {
    int i = blockIdx.x * 256 + threadIdx.x;          // 131072
    int t = i >> 8, b = i & 255;
    xT[i] = x[b * S_ + t];
}

__device__ __forceinline__ float sigmoid_f(float x) { return 1.0f / (1.0f + __expf(-x)); }
__device__ __forceinline__ float tanh_f(float x)    { return 2.0f / (1.0f + __expf(-2.0f * x)) - 1.0f; }

__device__ __forceinline__ float bf2f(unsigned short u) {
    union { unsigned i; float f; } x; x.i = ((unsigned)u) << 16; return x.f;
}
__device__ __forceinline__ unsigned short f2bf(float f) {
    union { __hip_bfloat16 h; unsigned short s; } x; x.h = __float2bfloat16(f); return x.s;
}

// LLC-direct, fully-pipelined h-fragment load.
#define LOADH(kc, g, off)                                                        \
    asm volatile("global_load_dwordx4 %0, %1, off offset:" #off " sc0 sc1"       \
                 : "=v"(hfrag[kc]) : "v"(hb[g]));

// counted wait + full scheduling fence (rule #18: MFMA must not hoist past the wait)
#define WAITV(n)                                                                 \
    asm volatile("s_waitcnt vmcnt(" #n ")" ::: "memory");                        \
    __builtin_amdgcn_sched_barrier(0);

#define MM(kc) {                                                                 \
    s8v hv = hfrag[kc];                                                          \
    acc0 = __builtin_amdgcn_mfma_f32_16x16x32_bf16(Wlds[0 * 2048 + (kc) * 64 + l], hv, acc0, 0, 0, 0); \
    acc1 = __builtin_amdgcn_mfma_f32_16x16x32_bf16(Wlds[1 * 2048 + (kc) * 64 + l], hv, acc1, 0, 0, 0); \
    acc2 = __builtin_amdgcn_mfma_f32_16x16x32_bf16(Wlds[2 * 2048 + (kc) * 64 + l], hv, acc2, 0, 0, 0); \
    acc3 = __builtin_amdgcn_mfma_f32_16x16x32_bf16(Wlds[3 * 2048 + (kc) * 64 + l], hv, acc3, 0, 0, 0); }

__global__ __launch_bounds__(256, 1) void lstm_main(
    const float* __restrict__ xT,
    const float* __restrict__ wgx, const float* __restrict__ wix,
    const float* __restrict__ wfx, const float* __restrict__ wox,
    const float* __restrict__ bg,  const float* __restrict__ bi,
    const float* __restrict__ bf,  const float* __restrict__ bo,
    const __hip_bfloat16* __restrict__ Wp,
    __hip_bfloat16* __restrict__ h0, __hip_bfloat16* __restrict__ h1,
    const float* __restrict__ wph, const float* __restrict__ bp,
    float* __restrict__ out,
    unsigned* __restrict__ flags)
{
    // weights LDS-stationary: 4 gates x 32 kc x 64 lanes x 16B = 128 KB
    __shared__ s8v Wlds[4 * 32 * 64];
    __shared__ unsigned done_cnt;   // monotonic: wave-step completions of this block
    __shared__ unsigned tok;        // monotonic: 2t+1 = chunks 0..15 ready, 2t+2 = all

    const int tid  = threadIdx.x;
    const int wgid = blockIdx.x;         // 256 blocks
    const int m    = wgid >> 6;          // batch group 0..3 (64 rows)
    const int n    = wgid & 63;          // out-tile 0..63 (16 hidden cols per gate)
    const int w    = tid >> 6;           // wave 0..3 (batch sub-tile); wave 0 also polls
    const int l    = tid & 63;
    const int quad = l >> 4;
    const int l16  = l & 15;
    const int b    = m * 64 + w * 16 + l16;  // this lane's batch row
    const int out0 = n * 16 + quad * 4;      // first of this lane's 4 hidden cols

    if (tid == 0) { done_cnt = 0u; tok = 0u; }

    // one-time: stage this block's weights into LDS (coalesced 16B cached loads)
    {
        const s8v* Wv = (const s8v*)Wp;
#pragma unroll
        for (int j = 0; j < 32; ++j) {
            int idx = j * 256 + tid;             // 0..8191
            int g   = idx >> 11;
            int rem = idx & 2047;                // kc*64 + lane
            Wlds[g * 2048 + rem] = Wv[((g * 64 + n) * 32) * 64 + rem];
        }
    }

    // per-lane gate params for the 4 consecutive hidden cols
    float wxg[4], wxi[4], wxf[4], wxo[4], bbg[4], bbi[4], bbf[4], bbo[4];
    *(float4*)wxg = *(const float4*)(wgx + out0);
    *(float4*)wxi = *(const float4*)(wix + out0);
    *(float4*)wxf = *(const float4*)(wfx + out0);
    *(float4*)wxo = *(const float4*)(wox + out0);
    *(float4*)bbg = *(const float4*)(bg + out0);
    *(float4*)bbi = *(const float4*)(bi + out0);
    *(float4*)bbf = *(const float4*)(bf + out0);
    *(float4*)bbo = *(const float4*)(bo + out0);

    float cs[4] = {0.f, 0.f, 0.f, 0.f};     // persistent cell state

    const unsigned* flp = flags + (u64)(m * 64 + l) * 32;   // lane l watches block (m,l)
    unsigned* myflag    = flags + (u64)(m * 64 + n) * 32;

    // fragment-linear base offsets
    const u64 tbOff = (u64)((m * 4 + w) * 32768) + (u64)l * 16;   // consumer load base
    const int eidx_s = ((m * 4 + w) * 32 + (out0 >> 5)) * 64 + ((out0 >> 3) & 3) * 16 + l16;
    const u64 stOff  = (u64)eidx_s * 16 + (u64)(out0 & 7) * 2;    // producer store offset
    u64 xaddr = (u64)(const void*)xT + (u64)b * 4;                // xT[t*B + b], t=0
    const u64 h0a = (u64)(const void*)h0;
    const u64 h1a = (u64)(const void*)h1;

    __syncthreads();                         // LDS weights + done_cnt/tok ready

    // prefetch xa for t=0 (oldest in-flight; counted waits account for it)
    float xa_cur, xa_nxt;
    asm volatile("global_load_dword %0, %1, off" : "=v"(xa_cur) : "v"(xaddr));

    for (int t = 0; t < S_; ++t) {
        const unsigned tu = (unsigned)t;
        const u64 hinB  = (t & 1) ? h1a : h0a;
        const u64 houtB = (t & 1) ? h0a : h1a;

        bool fd = false;                     // "all 64 done" seen at stage-1 detect

        // ---- stage 1: blocks 0..31 done -> chunks kc 0..15 readable; the same
        //      ballot covers all 64 lanes, so detect full-group completion for free ----
        if (w == 0) {
            for (;;) {
                unsigned v = __hip_atomic_load(flp, __ATOMIC_RELAXED,
                                               __HIP_MEMORY_SCOPE_AGENT);
                u64 bal = __ballot(v < tu);
                if ((bal & 0xFFFFFFFFull) == 0ull) { fd = (bal == 0ull); break; }
                __builtin_amdgcn_s_sleep(1);
            }
            if (l == 0)
                __hip_atomic_store(&tok, fd ? 2u * tu + 2u : 2u * tu + 1u,
                                   __ATOMIC_RELAXED, __HIP_MEMORY_SCOPE_WORKGROUP);
        } else {
            while (__hip_atomic_load(&tok, __ATOMIC_RELAXED,
                                     __HIP_MEMORY_SCOPE_WORKGROUP) < 2u * tu + 1u) { }
        }
        __builtin_amdgcn_sched_barrier(0);

        // 8 base addresses (13-bit imm offset only reaches 4095; kc stride is 1024B)
        u64 hb[8];
        u64 base = hinB + tbOff;
#pragma unroll
        for (int g = 0; g < 8; ++g) hb[g] = base + (u64)g * 4096;

        s8v hfrag[32];
        // batch-1 loads (kc 0..15): RTT overlaps the straggler tail of blocks 32..63
        LOADH( 0, 0, 0) LOADH( 1, 0, 1024) LOADH( 2, 0, 2048) LOADH( 3, 0, 3072)
        LOADH( 4, 1, 0) LOADH( 5, 1, 1024) LOADH( 6, 1, 2048) LOADH( 7, 1, 3072)
        LOADH( 8, 2, 0) LOADH( 9, 2, 1024) LOADH(10, 2, 2048) LOADH(11, 2, 3072)
        LOADH(12, 3, 0) LOADH(13, 3, 1024) LOADH(14, 3, 2048) LOADH(15, 3, 3072)

        // ---- stage 2: all 64 blocks done (skipped when stage-1 already saw all 64) ----
        if (w == 0) {
            if (!fd) {
                for (;;) {
                    unsigned v = __hip_atomic_load(flp, __ATOMIC_RELAXED,
                                                   __HIP_MEMORY_SCOPE_AGENT);
                    if (__ballot(v < tu) == 0ull) break;
                    __builtin_amdgcn_s_sleep(1);
                }
                if (l == 0)
                    __hip_atomic_store(&tok, 2u * tu + 2u, __ATOMIC_RELAXED,
                                       __HIP_MEMORY_SCOPE_WORKGROUP);
            }
        } else {
            while (__hip_atomic_load(&tok, __ATOMIC_RELAXED,
                                     __HIP_MEMORY_SCOPE_WORKGROUP) < 2u * tu + 2u) { }
        }
        __builtin_amdgcn_sched_barrier(0);

        LOADH(16, 4, 0) LOADH(17, 4, 1024) LOADH(18, 4, 2048) LOADH(19, 4, 3072)
        LOADH(20, 5, 0) LOADH(21, 5, 1024) LOADH(22, 5, 2048) LOADH(23, 5, 3072)
        LOADH(24, 6, 0) LOADH(25, 6, 1024) LOADH(26, 6, 2048) LOADH(27, 6, 3072)
        LOADH(28, 7, 0) LOADH(29, 7, 1024) LOADH(30, 7, 2048) LOADH(31, 7, 3072)

        f4v acc0 = {0.f, 0.f, 0.f, 0.f}, acc1 = acc0, acc2 = acc0, acc3 = acc0;
        // Outstanding entering the ladder (per wave): <= flag-store + xa + 32 frags.
        // Older non-frag entries (flag, xa) only make the counted waits conservative:
        // WAITV(24) retires all but the newest 24 -> kc 0..7 landed, etc.
        WAITV(24)
        MM(0)  MM(1)  MM(2)  MM(3)  MM(4)  MM(5)  MM(6)  MM(7)
        WAITV(16)
        MM(8)  MM(9)  MM(10) MM(11) MM(12) MM(13) MM(14) MM(15)
        WAITV(8)
        MM(16) MM(17) MM(18) MM(19) MM(20) MM(21) MM(22) MM(23)
        WAITV(0)
        MM(24) MM(25) MM(26) MM(27) MM(28) MM(29) MM(30) MM(31)

        // epilogue: D row (quad*4+r) = hidden col out0+r, D col (l16) = batch b
        // xa_cur landed (WAITV(0) drained everything).
        float xa = xa_cur;
        unsigned short hs[4];
#pragma unroll
        for (int r = 0; r < 4; ++r) {
            float pg = acc0[r] + xa * wxg[r] + bbg[r];
            float pi = acc1[r] + xa * wxi[r] + bbi[r];
            float pf = acc2[r] + xa * wxf[r] + bbf[r];
            float po = acc3[r] + xa * wxo[r] + bbo[r];
            float gv = tanh_f(pg);
            float iv = sigmoid_f(pi);
            float fv = sigmoid_f(pf);
            float ov = sigmoid_f(po);
            float cn = gv * iv + cs[r] * fv;
            cs[r] = cn;
            hs[r] = f2bf(tanh_f(cn) * ov);
        }
        union { unsigned short s[4]; u64 q; } hp_;
        hp_.s[0] = hs[0]; hp_.s[1] = hs[1]; hp_.s[2] = hs[2]; hp_.s[3] = hs[3];
        // one 8B write-through (LLC) store into the fragment-linear slot
        __hip_atomic_store((u64*)(houtB + stOff), hp_.q,
                           __ATOMIC_RELAXED, __HIP_MEMORY_SCOPE_AGENT);

        // drain the h store, publish via the LDS chain (single flag store per block,
        // by the 4th-draining wave), THEN issue the next xa prefetch - its RTT is off
        // the publish edge. Flag store + xa stay in flight (oldest entries next iter).
        asm volatile("s_waitcnt vmcnt(0)" ::: "memory");
        if (l == 0) {
            unsigned old = __hip_atomic_fetch_add(&done_cnt, 1u, __ATOMIC_RELAXED,
                                                  __HIP_MEMORY_SCOPE_WORKGROUP);
            if (old == 4u * tu + 3u)
                __hip_atomic_store(myflag, tu + 1u, __ATOMIC_RELAXED,
                                   __HIP_MEMORY_SCOPE_AGENT);
        }
        xaddr += (u64)B_ * 4;
        asm volatile("global_load_dword %0, %1, off" : "=v"(xa_nxt) : "v"(xaddr));
        xa_cur = xa_nxt;
    }

    // ---- final rendezvous: all blocks of the group done with step S-1 ----
    if (w == 0) {
        for (;;) {
            unsigned v = __hip_atomic_load(flp, __ATOMIC_RELAXED,
                                           __HIP_MEMORY_SCOPE_AGENT);
            if (__ballot(v < (unsigned)S_) == 0ull) break;
            __builtin_amdgcn_s_sleep(1);
        }
        if (l == 0)
            __hip_atomic_store(&tok, 2u * (unsigned)S_ + 1u, __ATOMIC_RELAXED,
                               __HIP_MEMORY_SCOPE_WORKGROUP);
    }
    while (__hip_atomic_load(&tok, __ATOMIC_RELAXED,
                             __HIP_MEMORY_SCOPE_WORKGROUP) < 2u * (unsigned)S_ + 1u) { }
    __builtin_amdgcn_sched_barrier(0);

    // projection restricted to own group's rows: out[row][cc], rows [64m, 64m+64)
    // final h is h0 (t=511 odd wrote h0); bypass atomic loads -> always fresh.
    const __hip_bfloat16* hf = h0;
    int wig = n * 4 + w;                     // wave index in group, 0..255
    for (int p = wig; p < 64 * C_; p += 256) {
        int row = m * 64 + p / C_;
        int cc  = p % C_;
        int tb  = row >> 4, bl = row & 15;
        const float* wr = wph + cc * H_;
        float acc = 0.f;
#pragma unroll
        for (int j = 0; j < 4; ++j) {
            int k   = j * 256 + l * 4;
            int kc  = k >> 5;
            int qd  = (k >> 3) & 3;
            const u64* hp = (const u64*)((const char*)hf
                              + ((size_t)((tb * 32 + kc) * 64 + qd * 16 + bl)) * 16
                              + (size_t)(k & 7) * 2);
            u64 hv4 = __hip_atomic_load(hp, __ATOMIC_RELAXED, __HIP_MEMORY_SCOPE_AGENT);
            union { u64 q; unsigned short s[4]; } u_; u_.q = hv4;
            float4 wv = *(const float4*)(wr + k);
            acc += bf2f(u_.s[0]) * wv.x + bf2f(u_.s[1]) * wv.y
                 + bf2f(u_.s[2]) * wv.z + bf2f(u_.s[3]) * wv.w;
        }
#pragma unroll
        for (int off = 32; off > 0; off >>= 1) acc += __shfl_down(acc, off, 64);
        if (l == 0) out[row * C_ + cc] = acc + bp[cc];
    }
}

extern "C" void kernel_launch(void* const* d_in, const int* in_sizes, int n_in,
                              void* d_out, int out_size, void* d_ws, size_t ws_size,
                              hipStream_t stream) {
    const float* x   = (const float*)d_in[0];
    const float* wgx = (const float*)d_in[1];
    const float* wix = (const float*)d_in[2];
    const float* wfx = (const float*)d_in[3];
    const float* wox = (const float*)d_in[4];
    const float* wgh = (const float*)d_in[5];
    const float* wih = (const float*)d_in[6];
    const float* wfh = (const float*)d_in[7];
    const float* woh = (const float*)d_in[8];
    const float* wph = (const float*)d_in[9];
    const float* bg  = (const float*)d_in[10];
    const float* bi  = (const float*)d_in[11];
    const float* bf  = (const float*)d_in[12];
    const float* bo  = (const float*)d_in[13];
    const float* bp  = (const float*)d_in[14];
    float* out = (float*)d_out;

    char* ws = (char*)d_ws;
    unsigned*       flags = (unsigned*)ws;
    float*          xT    = (float*)(ws + 32768);
    __hip_bfloat16* h0    = (__hip_bfloat16*)(ws + 32768 + 524288);
    __hip_bfloat16* h1    = (__hip_bfloat16*)(ws + 32768 + 2 * 524288);
    __hip_bfloat16* Wp    = (__hip_bfloat16*)(ws + 32768 + 3 * 524288);

    hipMemsetAsync(flags, 0, 32768, stream);              // spread flags = 0
    hipMemsetAsync(h0, 0, 524288, stream);                // h_0 = 0
    prep_x<<<512, 256, 0, stream>>>(x, xT);
    prep_w<<<2048, 256, 0, stream>>>(wgh, wih, wfh, woh, Wp);
    lstm_main<<<256, 256, 0, stream>>>(xT, wgx, wix, wfx, wox, bg, bi, bf, bo,
                                       Wp, h0, h1, wph, bp, out, flags);
}